// Round 3
// baseline (364.930 us; speedup 1.0000x reference)
//
#include <hip/hip_runtime.h>
#include <hip/hip_bf16.h>
#include <cstdint>
#include <cstddef>

#define BT    16384   // B*T
#define DIN   4096
#define DOUT  4096
#define RR    64
#define TSEQ  2048

typedef float  f32x4  __attribute__((ext_vector_type(4)));
typedef __bf16 bf16x8 __attribute__((ext_vector_type(8)));

// ---------------------------------------------------------------------------
// k_xa: inter[m][r] = bf16( sum_k x[m][k] * A[a][k][r] )
// grid 1024 blocks (16 m-rows each), 256 thr = 4 waves; wave rw owns r-tile
// [rw*16, rw*16+16), full K sweep. No LDS. A fragments via 8 strided scalar
// fp32 loads (lane-adjacent r -> 64B coalesced segments), converted to bf16.
// ---------------------------------------------------------------------------
__global__ __launch_bounds__(256) void k_xa(
    const float* __restrict__ x, const int* __restrict__ idx,
    const float* __restrict__ A, __bf16* __restrict__ inter)
{
    const int m0   = blockIdx.x * 16;
    const int a    = idx[m0 / TSEQ];
    const float* __restrict__ Aa = A + (size_t)a * DIN * RR;
    const int lane = threadIdx.x & 63;
    const int rw   = threadIdx.x >> 6;          // wave id 0..3 -> r-tile
    const int mr   = lane & 15, kg = lane >> 4; // row-in-tile, k-group
    const int rcol = rw * 16 + mr;              // this lane's r column
    const float* __restrict__ xrow = x + (size_t)(m0 + mr) * DIN;

    f32x4 acc = {0.f, 0.f, 0.f, 0.f};

    for (int k0 = 0; k0 < DIN; k0 += 64) {
        #pragma unroll
        for (int ksub = 0; ksub < 2; ++ksub) {
            const int koff = k0 + ksub * 32 + kg * 8;
            // x fragment (A-operand): row m0+mr, k = koff..koff+7
            float4 u0 = *(const float4*)&xrow[koff];
            float4 u1 = *(const float4*)&xrow[koff + 4];
            bf16x8 af;
            af[0] = (__bf16)u0.x; af[1] = (__bf16)u0.y;
            af[2] = (__bf16)u0.z; af[3] = (__bf16)u0.w;
            af[4] = (__bf16)u1.x; af[5] = (__bf16)u1.y;
            af[6] = (__bf16)u1.z; af[7] = (__bf16)u1.w;
            // A fragment (B-operand): col rcol, k = koff..koff+7 (stride RR)
            const float* ap = &Aa[(size_t)koff * RR + rcol];
            bf16x8 bf;
            bf[0] = (__bf16)ap[0 * RR]; bf[1] = (__bf16)ap[1 * RR];
            bf[2] = (__bf16)ap[2 * RR]; bf[3] = (__bf16)ap[3 * RR];
            bf[4] = (__bf16)ap[4 * RR]; bf[5] = (__bf16)ap[5 * RR];
            bf[6] = (__bf16)ap[6 * RR]; bf[7] = (__bf16)ap[7 * RR];
            acc = __builtin_amdgcn_mfma_f32_16x16x32_bf16(af, bf, acc, 0, 0, 0);
        }
    }

    // D layout: col = lane&15 (rcol), row = kg*4 + q
    #pragma unroll
    for (int q = 0; q < 4; ++q)
        inter[(size_t)(m0 + kg * 4 + q) * RR + rcol] = (__bf16)acc[q];
}

// ---------------------------------------------------------------------------
// k_by: out[m][o] = base[m][o] + s * sum_r inter[m][r] * B[a][r][o]
// grid (DOUT/64, BT/64) = (64,256), 256 thr = 4 waves; wave w owns o-tile
// [o0+w*16, +16) x all 64 m-rows. No LDS. B fragments via 8 strided scalar
// fp32 loads (lane-adjacent o -> 64B coalesced segments).
// ---------------------------------------------------------------------------
__global__ __launch_bounds__(256) void k_by(
    const __bf16* __restrict__ inter, const float* __restrict__ base,
    const int* __restrict__ idx, const float* __restrict__ Bw,
    const float* __restrict__ scal, float* __restrict__ out)
{
    const int o0 = blockIdx.x * 64;
    const int m0 = blockIdx.y * 64;
    const int a  = idx[m0 / TSEQ];
    const float s = scal[a];
    const float* __restrict__ Ba = Bw + (size_t)a * RR * DOUT;
    const int lane = threadIdx.x & 63;
    const int w    = threadIdx.x >> 6;
    const int mr   = lane & 15, kg = lane >> 4;
    const int oc   = o0 + w * 16 + mr;          // this lane's o column

    f32x4 z = {0.f, 0.f, 0.f, 0.f};
    f32x4 acc[4] = {z, z, z, z};

    #pragma unroll
    for (int ksub = 0; ksub < 2; ++ksub) {
        const int kb = ksub * 32 + kg * 8;      // this lane's r-offset
        // B fragment (B-operand): col oc, k = kb..kb+7 (stride DOUT)
        const float* bp = &Ba[(size_t)kb * DOUT + oc];
        bf16x8 bf;
        bf[0] = (__bf16)bp[0 * DOUT]; bf[1] = (__bf16)bp[1 * DOUT];
        bf[2] = (__bf16)bp[2 * DOUT]; bf[3] = (__bf16)bp[3 * DOUT];
        bf[4] = (__bf16)bp[4 * DOUT]; bf[5] = (__bf16)bp[5 * DOUT];
        bf[6] = (__bf16)bp[6 * DOUT]; bf[7] = (__bf16)bp[7 * DOUT];
        #pragma unroll
        for (int mt = 0; mt < 4; ++mt) {
            // inter fragment (A-operand): row m0+mt*16+mr, k = kb..kb+7
            bf16x8 af = *(const bf16x8*)&inter[(size_t)(m0 + mt * 16 + mr) * RR + kb];
            acc[mt] = __builtin_amdgcn_mfma_f32_16x16x32_bf16(af, bf, acc[mt], 0, 0, 0);
        }
    }

    #pragma unroll
    for (int mt = 0; mt < 4; ++mt) {
        #pragma unroll
        for (int q = 0; q < 4; ++q) {
            size_t off = (size_t)(m0 + mt * 16 + kg * 4 + q) * DOUT + oc;
            out[off] = base[off] + s * acc[mt][q];
        }
    }
}

// ---------------------------------------------------------------------------
extern "C" void kernel_launch(void* const* d_in, const int* in_sizes, int n_in,
                              void* d_out, int out_size, void* d_ws, size_t ws_size,
                              hipStream_t stream)
{
    const float* x    = (const float*)d_in[0];
    const float* base = (const float*)d_in[1];
    const int*   idx  = (const int*)  d_in[2];
    const float* A    = (const float*)d_in[3];
    const float* Bw   = (const float*)d_in[4];
    const float* scal = (const float*)d_in[5];
    float* out = (float*)d_out;

    __bf16* inter = (__bf16*)d_ws;   // 16384*64*2 B = 2 MB (< 4 MB proven OK)

    k_xa<<<dim3(BT / 16),          256, 0, stream>>>(x, idx, A, inter);
    k_by<<<dim3(DOUT / 64, BT / 64), 256, 0, stream>>>(inter, base, idx, Bw, scal, out);
}

// Round 6
// 326.907 us; speedup vs baseline: 1.1163x; 1.1163x over previous
//
#include <hip/hip_runtime.h>
#include <hip/hip_bf16.h>
#include <cstdint>
#include <cstddef>

#define BT    16384   // B*T
#define DIN   4096
#define DOUT  4096
#define RR    64
#define TSEQ  2048

typedef float  f32x4  __attribute__((ext_vector_type(4)));
typedef __bf16 bf16x8 __attribute__((ext_vector_type(8)));

// ---------------------------------------------------------------------------
// k_xa: inter[m][r] = bf16( sum_k x[m][k] * A[a][k][r] )
// Structure = R3 (PASSED) with one delta: block owns 32 m-rows, each wave
// runs TWO independent chains (rows m0..m0+15 and m0+16..m0+31) sharing the
// B-operand fragment. Each chain is index-identical to R3's. No LDS.
// grid BT/32 = 512 blocks, 256 thr = 4 waves; wave rw owns r-tile rw*16.
// ---------------------------------------------------------------------------
__global__ __launch_bounds__(256) void k_xa(
    const float* __restrict__ x, const int* __restrict__ idx,
    const float* __restrict__ A, __bf16* __restrict__ inter)
{
    const int m0   = blockIdx.x * 32;
    const int a    = idx[m0 / TSEQ];
    const float* __restrict__ Aa = A + (size_t)a * DIN * RR;
    const int lane = threadIdx.x & 63;
    const int rw   = threadIdx.x >> 6;          // wave id 0..3 -> r-tile
    const int mr   = lane & 15, kg = lane >> 4; // row-in-tile, k-group
    const int rcol = rw * 16 + mr;              // this lane's r column
    const float* __restrict__ xrow0 = x + (size_t)(m0 + mr) * DIN;
    const float* __restrict__ xrow1 = x + (size_t)(m0 + 16 + mr) * DIN;

    f32x4 acc0 = {0.f, 0.f, 0.f, 0.f};
    f32x4 acc1 = {0.f, 0.f, 0.f, 0.f};

    for (int k0 = 0; k0 < DIN; k0 += 64) {
        #pragma unroll
        for (int ksub = 0; ksub < 2; ++ksub) {
            const int koff = k0 + ksub * 32 + kg * 8;
            // x fragments (A-operand), rows m0+mr and m0+16+mr, k=koff..+7
            float4 u0 = *(const float4*)&xrow0[koff];
            float4 u1 = *(const float4*)&xrow0[koff + 4];
            float4 v0 = *(const float4*)&xrow1[koff];
            float4 v1 = *(const float4*)&xrow1[koff + 4];
            bf16x8 af0, af1;
            af0[0] = (__bf16)u0.x; af0[1] = (__bf16)u0.y;
            af0[2] = (__bf16)u0.z; af0[3] = (__bf16)u0.w;
            af0[4] = (__bf16)u1.x; af0[5] = (__bf16)u1.y;
            af0[6] = (__bf16)u1.z; af0[7] = (__bf16)u1.w;
            af1[0] = (__bf16)v0.x; af1[1] = (__bf16)v0.y;
            af1[2] = (__bf16)v0.z; af1[3] = (__bf16)v0.w;
            af1[4] = (__bf16)v1.x; af1[5] = (__bf16)v1.y;
            af1[6] = (__bf16)v1.z; af1[7] = (__bf16)v1.w;
            // A fragment (B-operand): col rcol, k = koff..+7 (stride RR),
            // SHARED by both chains.
            const float* ap = &Aa[(size_t)koff * RR + rcol];
            bf16x8 bf;
            bf[0] = (__bf16)ap[0 * RR]; bf[1] = (__bf16)ap[1 * RR];
            bf[2] = (__bf16)ap[2 * RR]; bf[3] = (__bf16)ap[3 * RR];
            bf[4] = (__bf16)ap[4 * RR]; bf[5] = (__bf16)ap[5 * RR];
            bf[6] = (__bf16)ap[6 * RR]; bf[7] = (__bf16)ap[7 * RR];
            acc0 = __builtin_amdgcn_mfma_f32_16x16x32_bf16(af0, bf, acc0, 0, 0, 0);
            acc1 = __builtin_amdgcn_mfma_f32_16x16x32_bf16(af1, bf, acc1, 0, 0, 0);
        }
    }

    // D layout: col = lane&15 (rcol), row = kg*4 + q  (identical to R3)
    #pragma unroll
    for (int q = 0; q < 4; ++q) {
        inter[(size_t)(m0 + kg * 4 + q) * RR + rcol]      = (__bf16)acc0[q];
        inter[(size_t)(m0 + 16 + kg * 4 + q) * RR + rcol] = (__bf16)acc1[q];
    }
}

// ---------------------------------------------------------------------------
// k_by: out[m][o] = base[m][o] + s * sum_r inter[m][r] * B[a][r][o]
// R3 VERBATIM (passed). grid (DOUT/64, BT/64) = (64,256), 4 waves;
// wave w owns o-tile [o0+w*16,+16) x 64 m-rows. No LDS.
// ---------------------------------------------------------------------------
__global__ __launch_bounds__(256) void k_by(
    const __bf16* __restrict__ inter, const float* __restrict__ base,
    const int* __restrict__ idx, const float* __restrict__ Bw,
    const float* __restrict__ scal, float* __restrict__ out)
{
    const int o0 = blockIdx.x * 64;
    const int m0 = blockIdx.y * 64;
    const int a  = idx[m0 / TSEQ];
    const float s = scal[a];
    const float* __restrict__ Ba = Bw + (size_t)a * RR * DOUT;
    const int lane = threadIdx.x & 63;
    const int w    = threadIdx.x >> 6;
    const int mr   = lane & 15, kg = lane >> 4;
    const int oc   = o0 + w * 16 + mr;          // this lane's o column

    f32x4 z = {0.f, 0.f, 0.f, 0.f};
    f32x4 acc[4] = {z, z, z, z};

    #pragma unroll
    for (int ksub = 0; ksub < 2; ++ksub) {
        const int kb = ksub * 32 + kg * 8;      // this lane's r-offset
        const float* bp = &Ba[(size_t)kb * DOUT + oc];
        bf16x8 bf;
        bf[0] = (__bf16)bp[0 * DOUT]; bf[1] = (__bf16)bp[1 * DOUT];
        bf[2] = (__bf16)bp[2 * DOUT]; bf[3] = (__bf16)bp[3 * DOUT];
        bf[4] = (__bf16)bp[4 * DOUT]; bf[5] = (__bf16)bp[5 * DOUT];
        bf[6] = (__bf16)bp[6 * DOUT]; bf[7] = (__bf16)bp[7 * DOUT];
        #pragma unroll
        for (int mt = 0; mt < 4; ++mt) {
            bf16x8 af = *(const bf16x8*)&inter[(size_t)(m0 + mt * 16 + mr) * RR + kb];
            acc[mt] = __builtin_amdgcn_mfma_f32_16x16x32_bf16(af, bf, acc[mt], 0, 0, 0);
        }
    }

    #pragma unroll
    for (int mt = 0; mt < 4; ++mt) {
        #pragma unroll
        for (int q = 0; q < 4; ++q) {
            size_t off = (size_t)(m0 + mt * 16 + kg * 4 + q) * DOUT + oc;
            out[off] = base[off] + s * acc[mt][q];
        }
    }
}

// ---------------------------------------------------------------------------
extern "C" void kernel_launch(void* const* d_in, const int* in_sizes, int n_in,
                              void* d_out, int out_size, void* d_ws, size_t ws_size,
                              hipStream_t stream)
{
    const float* x    = (const float*)d_in[0];
    const float* base = (const float*)d_in[1];
    const int*   idx  = (const int*)  d_in[2];
    const float* A    = (const float*)d_in[3];
    const float* Bw   = (const float*)d_in[4];
    const float* scal = (const float*)d_in[5];
    float* out = (float*)d_out;

    __bf16* inter = (__bf16*)d_ws;   // 2 MB scratch

    k_xa<<<dim3(BT / 32),            256, 0, stream>>>(x, idx, A, inter);
    k_by<<<dim3(DOUT / 64, BT / 64), 256, 0, stream>>>(inter, base, idx, Bw, scal, out);
}

// Round 7
// 285.805 us; speedup vs baseline: 1.2768x; 1.1438x over previous
//
#include <hip/hip_runtime.h>
#include <hip/hip_bf16.h>
#include <cstdint>
#include <cstddef>

#define BT    16384   // B*T
#define DIN   4096
#define DOUT  4096
#define RR    64
#define TSEQ  2048
#define NADP  8

typedef float  f32x4  __attribute__((ext_vector_type(4)));
typedef __bf16 bf16x8 __attribute__((ext_vector_type(8)));

static __device__ __forceinline__ unsigned short bf16_bits(float f) {
    return __builtin_bit_cast(unsigned short, (__bf16)f);
}

// ---------------------------------------------------------------------------
// k_prep_a: At[a][r][k] = bf16(A[a][k][r]).  262144 threads, 8 k per thread.
// Reads coalesced along r; writes one 16B uint4 (8 packed bf16) per thread.
// ---------------------------------------------------------------------------
__global__ __launch_bounds__(256) void k_prep_a(
    const float* __restrict__ A, __bf16* __restrict__ At)
{
    const int gtid = blockIdx.x * 256 + threadIdx.x;
    const int r  = gtid & 63;
    const int kc = (gtid >> 6) & (DIN / 8 - 1);
    const int a  = gtid >> 15;
    const int k0 = kc * 8;
    const float* __restrict__ src = A + (size_t)a * DIN * RR + (size_t)k0 * RR + r;
    unsigned int u[4];
    #pragma unroll
    for (int p = 0; p < 4; ++p) {
        unsigned int lo = bf16_bits(src[(2 * p + 0) * RR]);
        unsigned int hi = bf16_bits(src[(2 * p + 1) * RR]);
        u[p] = lo | (hi << 16);
    }
    uint4 v = make_uint4(u[0], u[1], u[2], u[3]);
    *(uint4*)&At[(size_t)a * RR * DIN + (size_t)r * DIN + k0] = v;
}

// ---------------------------------------------------------------------------
// k_prep_b: Bt[a][o][r] = bf16(B[a][r][o]).  262144 threads, 8 r per thread.
// ---------------------------------------------------------------------------
__global__ __launch_bounds__(256) void k_prep_b(
    const float* __restrict__ Bw, __bf16* __restrict__ Bt)
{
    const int gtid = blockIdx.x * 256 + threadIdx.x;
    const int o  = gtid & (DOUT - 1);
    const int rc = (gtid >> 12) & 7;
    const int a  = gtid >> 15;
    const int r0 = rc * 8;
    const float* __restrict__ src = Bw + (size_t)a * RR * DOUT + (size_t)r0 * DOUT + o;
    unsigned int u[4];
    #pragma unroll
    for (int p = 0; p < 4; ++p) {
        unsigned int lo = bf16_bits(src[(2 * p + 0) * DOUT]);
        unsigned int hi = bf16_bits(src[(2 * p + 1) * DOUT]);
        u[p] = lo | (hi << 16);
    }
    uint4 v = make_uint4(u[0], u[1], u[2], u[3]);
    *(uint4*)&Bt[(size_t)a * DOUT * RR + (size_t)o * RR + r0] = v;
}

// ---------------------------------------------------------------------------
// k_xa: inter[m][r] = bf16( sum_k x[m][k] * At[a][r][k] )
// grid BT/64 = 256 blocks, 4 waves; wave w = m-tile [m0+w*16,+16) x 64 r,
// full K. 4 independent MFMA chains sharing the x fragment; weight fragment
// = one bf16x8 load. No LDS. Scalar bf16 output stores (passing construct).
// ---------------------------------------------------------------------------
__global__ __launch_bounds__(256) void k_xa(
    const float* __restrict__ x, const int* __restrict__ idx,
    const __bf16* __restrict__ At, __bf16* __restrict__ inter)
{
    const int m0   = blockIdx.x * 64;
    const int a    = idx[m0 / TSEQ];
    const int w    = threadIdx.x >> 6, lane = threadIdx.x & 63;
    const int mr   = lane & 15, kg = lane >> 4;
    const int mw   = m0 + w * 16;
    const float*  __restrict__ xrow = x  + (size_t)(mw + mr) * DIN;
    const __bf16* __restrict__ Aa   = At + (size_t)a * RR * DIN;

    f32x4 z = {0.f, 0.f, 0.f, 0.f};
    f32x4 acc[4] = {z, z, z, z};

    #pragma unroll 2
    for (int k0 = 0; k0 < DIN; k0 += 32) {
        const int koff = k0 + kg * 8;
        float4 u0 = *(const float4*)&xrow[koff];
        float4 u1 = *(const float4*)&xrow[koff + 4];
        bf16x8 af;
        af[0] = (__bf16)u0.x; af[1] = (__bf16)u0.y;
        af[2] = (__bf16)u0.z; af[3] = (__bf16)u0.w;
        af[4] = (__bf16)u1.x; af[5] = (__bf16)u1.y;
        af[6] = (__bf16)u1.z; af[7] = (__bf16)u1.w;
        #pragma unroll
        for (int n = 0; n < 4; ++n) {
            bf16x8 bf = *(const bf16x8*)&Aa[(size_t)(n * 16 + mr) * DIN + koff];
            acc[n] = __builtin_amdgcn_mfma_f32_16x16x32_bf16(af, bf, acc[n], 0, 0, 0);
        }
    }

    // D layout: row = kg*4+q (m within wave tile), col = n*16+mr (r)
    #pragma unroll
    for (int n = 0; n < 4; ++n)
        #pragma unroll
        for (int q = 0; q < 4; ++q)
            inter[(size_t)(mw + kg * 4 + q) * RR + n * 16 + mr] = (__bf16)acc[n][q];
}

// ---------------------------------------------------------------------------
// k_by: out[m][o] = base[m][o] + s * sum_r inter[m][r] * Bt[a][o][r]
// R3/R6 skeleton verbatim; only change: B fragment = one bf16x8 load from Bt.
// ---------------------------------------------------------------------------
__global__ __launch_bounds__(256) void k_by(
    const __bf16* __restrict__ inter, const float* __restrict__ base,
    const int* __restrict__ idx, const __bf16* __restrict__ Bt,
    const float* __restrict__ scal, float* __restrict__ out)
{
    const int o0 = blockIdx.x * 64;
    const int m0 = blockIdx.y * 64;
    const int a  = idx[m0 / TSEQ];
    const float s = scal[a];
    const __bf16* __restrict__ Ba = Bt + (size_t)a * DOUT * RR;
    const int lane = threadIdx.x & 63;
    const int w    = threadIdx.x >> 6;
    const int mr   = lane & 15, kg = lane >> 4;
    const int oc   = o0 + w * 16 + mr;

    f32x4 z = {0.f, 0.f, 0.f, 0.f};
    f32x4 acc[4] = {z, z, z, z};

    #pragma unroll
    for (int ksub = 0; ksub < 2; ++ksub) {
        const int kb = ksub * 32 + kg * 8;
        bf16x8 bf = *(const bf16x8*)&Ba[(size_t)oc * RR + kb];
        #pragma unroll
        for (int mt = 0; mt < 4; ++mt) {
            bf16x8 af = *(const bf16x8*)&inter[(size_t)(m0 + mt * 16 + mr) * RR + kb];
            acc[mt] = __builtin_amdgcn_mfma_f32_16x16x32_bf16(af, bf, acc[mt], 0, 0, 0);
        }
    }

    #pragma unroll
    for (int mt = 0; mt < 4; ++mt) {
        #pragma unroll
        for (int q = 0; q < 4; ++q) {
            size_t off = (size_t)(m0 + mt * 16 + kg * 4 + q) * DOUT + oc;
            out[off] = base[off] + s * acc[mt][q];
        }
    }
}

// ---------------------------------------------------------------------------
// Fallback kernels (R6 verbatim, 2 MB ws) if ws_size < 10 MB.
// ---------------------------------------------------------------------------
__global__ __launch_bounds__(256) void k_xa_fb(
    const float* __restrict__ x, const int* __restrict__ idx,
    const float* __restrict__ A, __bf16* __restrict__ inter)
{
    const int m0   = blockIdx.x * 32;
    const int a    = idx[m0 / TSEQ];
    const float* __restrict__ Aa = A + (size_t)a * DIN * RR;
    const int lane = threadIdx.x & 63;
    const int rw   = threadIdx.x >> 6;
    const int mr   = lane & 15, kg = lane >> 4;
    const int rcol = rw * 16 + mr;
    const float* __restrict__ xrow0 = x + (size_t)(m0 + mr) * DIN;
    const float* __restrict__ xrow1 = x + (size_t)(m0 + 16 + mr) * DIN;

    f32x4 acc0 = {0.f, 0.f, 0.f, 0.f};
    f32x4 acc1 = {0.f, 0.f, 0.f, 0.f};

    for (int k0 = 0; k0 < DIN; k0 += 64) {
        #pragma unroll
        for (int ksub = 0; ksub < 2; ++ksub) {
            const int koff = k0 + ksub * 32 + kg * 8;
            float4 u0 = *(const float4*)&xrow0[koff];
            float4 u1 = *(const float4*)&xrow0[koff + 4];
            float4 v0 = *(const float4*)&xrow1[koff];
            float4 v1 = *(const float4*)&xrow1[koff + 4];
            bf16x8 af0, af1;
            af0[0] = (__bf16)u0.x; af0[1] = (__bf16)u0.y;
            af0[2] = (__bf16)u0.z; af0[3] = (__bf16)u0.w;
            af0[4] = (__bf16)u1.x; af0[5] = (__bf16)u1.y;
            af0[6] = (__bf16)u1.z; af0[7] = (__bf16)u1.w;
            af1[0] = (__bf16)v0.x; af1[1] = (__bf16)v0.y;
            af1[2] = (__bf16)v0.z; af1[3] = (__bf16)v0.w;
            af1[4] = (__bf16)v1.x; af1[5] = (__bf16)v1.y;
            af1[6] = (__bf16)v1.z; af1[7] = (__bf16)v1.w;
            const float* ap = &Aa[(size_t)koff * RR + rcol];
            bf16x8 bf;
            bf[0] = (__bf16)ap[0 * RR]; bf[1] = (__bf16)ap[1 * RR];
            bf[2] = (__bf16)ap[2 * RR]; bf[3] = (__bf16)ap[3 * RR];
            bf[4] = (__bf16)ap[4 * RR]; bf[5] = (__bf16)ap[5 * RR];
            bf[6] = (__bf16)ap[6 * RR]; bf[7] = (__bf16)ap[7 * RR];
            acc0 = __builtin_amdgcn_mfma_f32_16x16x32_bf16(af0, bf, acc0, 0, 0, 0);
            acc1 = __builtin_amdgcn_mfma_f32_16x16x32_bf16(af1, bf, acc1, 0, 0, 0);
        }
    }
    #pragma unroll
    for (int q = 0; q < 4; ++q) {
        inter[(size_t)(m0 + kg * 4 + q) * RR + rcol]      = (__bf16)acc0[q];
        inter[(size_t)(m0 + 16 + kg * 4 + q) * RR + rcol] = (__bf16)acc1[q];
    }
}

__global__ __launch_bounds__(256) void k_by_fb(
    const __bf16* __restrict__ inter, const float* __restrict__ base,
    const int* __restrict__ idx, const float* __restrict__ Bw,
    const float* __restrict__ scal, float* __restrict__ out)
{
    const int o0 = blockIdx.x * 64;
    const int m0 = blockIdx.y * 64;
    const int a  = idx[m0 / TSEQ];
    const float s = scal[a];
    const float* __restrict__ Ba = Bw + (size_t)a * RR * DOUT;
    const int lane = threadIdx.x & 63;
    const int w    = threadIdx.x >> 6;
    const int mr   = lane & 15, kg = lane >> 4;
    const int oc   = o0 + w * 16 + mr;

    f32x4 z = {0.f, 0.f, 0.f, 0.f};
    f32x4 acc[4] = {z, z, z, z};

    #pragma unroll
    for (int ksub = 0; ksub < 2; ++ksub) {
        const int kb = ksub * 32 + kg * 8;
        const float* bp = &Ba[(size_t)kb * DOUT + oc];
        bf16x8 bf;
        bf[0] = (__bf16)bp[0 * DOUT]; bf[1] = (__bf16)bp[1 * DOUT];
        bf[2] = (__bf16)bp[2 * DOUT]; bf[3] = (__bf16)bp[3 * DOUT];
        bf[4] = (__bf16)bp[4 * DOUT]; bf[5] = (__bf16)bp[5 * DOUT];
        bf[6] = (__bf16)bp[6 * DOUT]; bf[7] = (__bf16)bp[7 * DOUT];
        #pragma unroll
        for (int mt = 0; mt < 4; ++mt) {
            bf16x8 af = *(const bf16x8*)&inter[(size_t)(m0 + mt * 16 + mr) * RR + kb];
            acc[mt] = __builtin_amdgcn_mfma_f32_16x16x32_bf16(af, bf, acc[mt], 0, 0, 0);
        }
    }
    #pragma unroll
    for (int mt = 0; mt < 4; ++mt) {
        #pragma unroll
        for (int q = 0; q < 4; ++q) {
            size_t off = (size_t)(m0 + mt * 16 + kg * 4 + q) * DOUT + oc;
            out[off] = base[off] + s * acc[mt][q];
        }
    }
}

// ---------------------------------------------------------------------------
extern "C" void kernel_launch(void* const* d_in, const int* in_sizes, int n_in,
                              void* d_out, int out_size, void* d_ws, size_t ws_size,
                              hipStream_t stream)
{
    const float* x    = (const float*)d_in[0];
    const float* base = (const float*)d_in[1];
    const int*   idx  = (const int*)  d_in[2];
    const float* A    = (const float*)d_in[3];
    const float* Bw   = (const float*)d_in[4];
    const float* scal = (const float*)d_in[5];
    float* out = (float*)d_out;

    const size_t INTER_B = (size_t)BT * RR * 2;              // 2 MB
    const size_t AT_B    = (size_t)NADP * RR * DIN * 2;      // 4 MB
    const size_t BT_B    = (size_t)NADP * DOUT * RR * 2;     // 4 MB

    __bf16* inter = (__bf16*)d_ws;

    if (ws_size >= INTER_B + AT_B + BT_B) {
        __bf16* At = (__bf16*)((char*)d_ws + INTER_B);
        __bf16* Bt = (__bf16*)((char*)d_ws + INTER_B + AT_B);
        k_prep_a<<<dim3(1024), 256, 0, stream>>>(A, At);
        k_prep_b<<<dim3(1024), 256, 0, stream>>>(Bw, Bt);
        k_xa<<<dim3(BT / 64),            256, 0, stream>>>(x, idx, At, inter);
        k_by<<<dim3(DOUT / 64, BT / 64), 256, 0, stream>>>(inter, base, idx, Bt, scal, out);
    } else {
        k_xa_fb<<<dim3(BT / 32),            256, 0, stream>>>(x, idx, A, inter);
        k_by_fb<<<dim3(DOUT / 64, BT / 64), 256, 0, stream>>>(inter, base, idx, Bw, scal, out);
    }
}

// Round 8
// 285.326 us; speedup vs baseline: 1.2790x; 1.0017x over previous
//
#include <hip/hip_runtime.h>
#include <hip/hip_bf16.h>
#include <cstdint>
#include <cstddef>

#define BT    16384   // B*T
#define DIN   4096
#define DOUT  4096
#define RR    64
#define TSEQ  2048
#define NADP  8

typedef float  f32x4  __attribute__((ext_vector_type(4)));
typedef __bf16 bf16x8 __attribute__((ext_vector_type(8)));

static __device__ __forceinline__ unsigned short bf16_bits(float f) {
    return __builtin_bit_cast(unsigned short, (__bf16)f);
}

// inter2 swizzled layout: [mblk(1024)][rb(8)][mrow(16)][j(8)]
// holds inter[mblk*16+mrow][rb*8+j]
static __device__ __forceinline__ size_t i2_idx(int mblk, int rb, int mrow, int j) {
    return ((((size_t)mblk * 8 + rb) * 16 + mrow) * 8 + j);
}

// ---------------------------------------------------------------------------
// k_prep_a: At2[a][kb][r][j] = bf16(A[a][kb*8+j][r]).  gtid = a*32768+kb*64+r.
// Reads coalesced along r; one 16B write per thread at At2 + gtid*8.
// ---------------------------------------------------------------------------
__global__ __launch_bounds__(256) void k_prep_a(
    const float* __restrict__ A, __bf16* __restrict__ At2)
{
    const int gtid = blockIdx.x * 256 + threadIdx.x;
    const int r  = gtid & 63;
    const int kb = (gtid >> 6) & (DIN / 8 - 1);
    const int a  = gtid >> 15;
    const float* __restrict__ src = A + (size_t)a * DIN * RR + (size_t)kb * 8 * RR + r;
    unsigned int u[4];
    #pragma unroll
    for (int p = 0; p < 4; ++p) {
        unsigned int lo = bf16_bits(src[(2 * p + 0) * RR]);
        unsigned int hi = bf16_bits(src[(2 * p + 1) * RR]);
        u[p] = lo | (hi << 16);
    }
    *(uint4*)&At2[(size_t)gtid * 8] = make_uint4(u[0], u[1], u[2], u[3]);
}

// ---------------------------------------------------------------------------
// k_prep_b: Bp[a][rb][o][j] = bf16(B[a][rb*8+j][o]).  gtid = a*32768+rb*4096+o.
// ---------------------------------------------------------------------------
__global__ __launch_bounds__(256) void k_prep_b(
    const float* __restrict__ Bw, __bf16* __restrict__ Bp)
{
    const int gtid = blockIdx.x * 256 + threadIdx.x;
    const int o  = gtid & (DOUT - 1);
    const int rb = (gtid >> 12) & 7;
    const int a  = gtid >> 15;
    const float* __restrict__ src = Bw + (size_t)a * RR * DOUT + (size_t)rb * 8 * DOUT + o;
    unsigned int u[4];
    #pragma unroll
    for (int p = 0; p < 4; ++p) {
        unsigned int lo = bf16_bits(src[(2 * p + 0) * DOUT]);
        unsigned int hi = bf16_bits(src[(2 * p + 1) * DOUT]);
        u[p] = lo | (hi << 16);
    }
    *(uint4*)&Bp[(size_t)gtid * 8] = make_uint4(u[0], u[1], u[2], u[3]);
}

// ---------------------------------------------------------------------------
// k_xa: inter[m][r] = bf16( sum_k x[m][k] * A[a][k][r] ), written to inter2.
// grid 1024 blocks (16 m-rows each), 4 waves; wave w owns r-tile [w*16,+16)
// (n-split -> 4 waves/SIMD TLP). Weight fragment = one 16B COALESCED load
// from At2. x fragments shared across waves via L1. Scalar bf16 stores.
// ---------------------------------------------------------------------------
__global__ __launch_bounds__(256) void k_xa(
    const float* __restrict__ x, const int* __restrict__ idx,
    const __bf16* __restrict__ At2, __bf16* __restrict__ inter2)
{
    const int m0   = blockIdx.x * 16;
    const int a    = idx[m0 / TSEQ];
    const int w    = threadIdx.x >> 6, lane = threadIdx.x & 63;
    const int mr   = lane & 15, kg = lane >> 4;
    const float*  __restrict__ xrow = x   + (size_t)(m0 + mr) * DIN;
    const __bf16* __restrict__ Aw   = At2 + (size_t)a * RR * DIN;

    f32x4 acc = {0.f, 0.f, 0.f, 0.f};

    #pragma unroll 4
    for (int k0 = 0; k0 < DIN; k0 += 32) {
        const int koff = k0 + kg * 8;
        float4 u0 = *(const float4*)&xrow[koff];
        float4 u1 = *(const float4*)&xrow[koff + 4];
        bf16x8 af;
        af[0] = (__bf16)u0.x; af[1] = (__bf16)u0.y;
        af[2] = (__bf16)u0.z; af[3] = (__bf16)u0.w;
        af[4] = (__bf16)u1.x; af[5] = (__bf16)u1.y;
        af[6] = (__bf16)u1.z; af[7] = (__bf16)u1.w;
        // B-operand: lane holds Aweight[k=koff..+7][r=w*16+mr]; 16B coalesced
        bf16x8 bf = *(const bf16x8*)&Aw[((size_t)(k0 / 8 + kg) * 64 + w * 16 + mr) * 8];
        acc = __builtin_amdgcn_mfma_f32_16x16x32_bf16(af, bf, acc, 0, 0, 0);
    }

    // D: row = kg*4+q (m-in-16), col = mr -> r = w*16+mr
    const int rb = w * 2 + (mr >> 3), j = mr & 7;
    #pragma unroll
    for (int q = 0; q < 4; ++q)
        inter2[i2_idx(blockIdx.x, rb, kg * 4 + q, j)] = (__bf16)acc[q];
}

// ---------------------------------------------------------------------------
// k_by: out[m][o] = base[m][o] + s * y[m][o],  y = inter @ B.
// grid (DOUT/64, BT/64), 4 waves; wave w = o-tile [o0+w*16,+16) x 64 m.
// OPERAND SWAP: acc = mfma(B_frag, inter_frag) computes y^T so each lane
// holds 4 CONSECUTIVE o's of one m-row -> float4 epilogue. All fragment
// loads are single 16B coalesced loads (Bp, inter2 layouts).
// ---------------------------------------------------------------------------
__global__ __launch_bounds__(256) void k_by(
    const __bf16* __restrict__ inter2, const float* __restrict__ base,
    const int* __restrict__ idx, const __bf16* __restrict__ Bp,
    const float* __restrict__ scal, float* __restrict__ out)
{
    const int o0 = blockIdx.x * 64;
    const int m0 = blockIdx.y * 64;
    const int a  = idx[m0 / TSEQ];
    const float s = scal[a];
    const __bf16* __restrict__ Ba = Bp + (size_t)a * RR * DOUT;
    const int lane = threadIdx.x & 63;
    const int w    = threadIdx.x >> 6;
    const int mr   = lane & 15, kg = lane >> 4;
    const int oc   = o0 + w * 16 + mr;

    f32x4 z = {0.f, 0.f, 0.f, 0.f};
    f32x4 acc[4] = {z, z, z, z};

    #pragma unroll
    for (int ksub = 0; ksub < 2; ++ksub) {
        const int rb = ksub * 4 + kg;
        // A-operand: lane holds Bw[k=rb*8+j][o=oc]; 16B coalesced
        bf16x8 bfA = *(const bf16x8*)&Ba[((size_t)rb * DOUT + oc) * 8];
        #pragma unroll
        for (int mt = 0; mt < 4; ++mt) {
            // B-operand: lane holds inter[m0+mt*16+mr][k=rb*8+j]; 16B coalesced
            bf16x8 afB = *(const bf16x8*)&inter2[i2_idx(m0 / 16 + mt, rb, mr, 0)];
            acc[mt] = __builtin_amdgcn_mfma_f32_16x16x32_bf16(bfA, afB, acc[mt], 0, 0, 0);
        }
    }

    // D': row = kg*4+q -> o = o0+w*16+kg*4+q (consecutive), col = mr -> m
    #pragma unroll
    for (int mt = 0; mt < 4; ++mt) {
        size_t off = (size_t)(m0 + mt * 16 + mr) * DOUT + o0 + w * 16 + kg * 4;
        float4 bv = *(const float4*)&base[off];
        float4 o;
        o.x = bv.x + s * acc[mt][0];
        o.y = bv.y + s * acc[mt][1];
        o.z = bv.z + s * acc[mt][2];
        o.w = bv.w + s * acc[mt][3];
        *(float4*)&out[off] = o;
    }
}

// ---------------------------------------------------------------------------
// Fallback kernels (R6 verbatim, 2 MB ws) if ws_size < 10 MB.
// ---------------------------------------------------------------------------
__global__ __launch_bounds__(256) void k_xa_fb(
    const float* __restrict__ x, const int* __restrict__ idx,
    const float* __restrict__ A, __bf16* __restrict__ inter)
{
    const int m0   = blockIdx.x * 32;
    const int a    = idx[m0 / TSEQ];
    const float* __restrict__ Aa = A + (size_t)a * DIN * RR;
    const int lane = threadIdx.x & 63;
    const int rw   = threadIdx.x >> 6;
    const int mr   = lane & 15, kg = lane >> 4;
    const int rcol = rw * 16 + mr;
    const float* __restrict__ xrow0 = x + (size_t)(m0 + mr) * DIN;
    const float* __restrict__ xrow1 = x + (size_t)(m0 + 16 + mr) * DIN;

    f32x4 acc0 = {0.f, 0.f, 0.f, 0.f};
    f32x4 acc1 = {0.f, 0.f, 0.f, 0.f};

    for (int k0 = 0; k0 < DIN; k0 += 64) {
        #pragma unroll
        for (int ksub = 0; ksub < 2; ++ksub) {
            const int koff = k0 + ksub * 32 + kg * 8;
            float4 u0 = *(const float4*)&xrow0[koff];
            float4 u1 = *(const float4*)&xrow0[koff + 4];
            float4 v0 = *(const float4*)&xrow1[koff];
            float4 v1 = *(const float4*)&xrow1[koff + 4];
            bf16x8 af0, af1;
            af0[0] = (__bf16)u0.x; af0[1] = (__bf16)u0.y;
            af0[2] = (__bf16)u0.z; af0[3] = (__bf16)u0.w;
            af0[4] = (__bf16)u1.x; af0[5] = (__bf16)u1.y;
            af0[6] = (__bf16)u1.z; af0[7] = (__bf16)u1.w;
            af1[0] = (__bf16)v0.x; af1[1] = (__bf16)v0.y;
            af1[2] = (__bf16)v0.z; af1[3] = (__bf16)v0.w;
            af1[4] = (__bf16)v1.x; af1[5] = (__bf16)v1.y;
            af1[6] = (__bf16)v1.z; af1[7] = (__bf16)v1.w;
            const float* ap = &Aa[(size_t)koff * RR + rcol];
            bf16x8 bf;
            bf[0] = (__bf16)ap[0 * RR]; bf[1] = (__bf16)ap[1 * RR];
            bf[2] = (__bf16)ap[2 * RR]; bf[3] = (__bf16)ap[3 * RR];
            bf[4] = (__bf16)ap[4 * RR]; bf[5] = (__bf16)ap[5 * RR];
            bf[6] = (__bf16)ap[6 * RR]; bf[7] = (__bf16)ap[7 * RR];
            acc0 = __builtin_amdgcn_mfma_f32_16x16x32_bf16(af0, bf, acc0, 0, 0, 0);
            acc1 = __builtin_amdgcn_mfma_f32_16x16x32_bf16(af1, bf, acc1, 0, 0, 0);
        }
    }
    #pragma unroll
    for (int q = 0; q < 4; ++q) {
        inter[(size_t)(m0 + kg * 4 + q) * RR + rcol]      = (__bf16)acc0[q];
        inter[(size_t)(m0 + 16 + kg * 4 + q) * RR + rcol] = (__bf16)acc1[q];
    }
}

__global__ __launch_bounds__(256) void k_by_fb(
    const __bf16* __restrict__ inter, const float* __restrict__ base,
    const int* __restrict__ idx, const float* __restrict__ Bw,
    const float* __restrict__ scal, float* __restrict__ out)
{
    const int o0 = blockIdx.x * 64;
    const int m0 = blockIdx.y * 64;
    const int a  = idx[m0 / TSEQ];
    const float s = scal[a];
    const float* __restrict__ Ba = Bw + (size_t)a * RR * DOUT;
    const int lane = threadIdx.x & 63;
    const int w    = threadIdx.x >> 6;
    const int mr   = lane & 15, kg = lane >> 4;
    const int oc   = o0 + w * 16 + mr;

    f32x4 z = {0.f, 0.f, 0.f, 0.f};
    f32x4 acc[4] = {z, z, z, z};

    #pragma unroll
    for (int ksub = 0; ksub < 2; ++ksub) {
        const int kb = ksub * 32 + kg * 8;
        const float* bp = &Ba[(size_t)kb * DOUT + oc];
        bf16x8 bf;
        bf[0] = (__bf16)bp[0 * DOUT]; bf[1] = (__bf16)bp[1 * DOUT];
        bf[2] = (__bf16)bp[2 * DOUT]; bf[3] = (__bf16)bp[3 * DOUT];
        bf[4] = (__bf16)bp[4 * DOUT]; bf[5] = (__bf16)bp[5 * DOUT];
        bf[6] = (__bf16)bp[6 * DOUT]; bf[7] = (__bf16)bp[7 * DOUT];
        #pragma unroll
        for (int mt = 0; mt < 4; ++mt) {
            bf16x8 af = *(const bf16x8*)&inter[(size_t)(m0 + mt * 16 + mr) * RR + kb];
            acc[mt] = __builtin_amdgcn_mfma_f32_16x16x32_bf16(af, bf, acc[mt], 0, 0, 0);
        }
    }
    #pragma unroll
    for (int mt = 0; mt < 4; ++mt) {
        #pragma unroll
        for (int q = 0; q < 4; ++q) {
            size_t off = (size_t)(m0 + mt * 16 + kg * 4 + q) * DOUT + oc;
            out[off] = base[off] + s * acc[mt][q];
        }
    }
}

// ---------------------------------------------------------------------------
extern "C" void kernel_launch(void* const* d_in, const int* in_sizes, int n_in,
                              void* d_out, int out_size, void* d_ws, size_t ws_size,
                              hipStream_t stream)
{
    const float* x    = (const float*)d_in[0];
    const float* base = (const float*)d_in[1];
    const int*   idx  = (const int*)  d_in[2];
    const float* A    = (const float*)d_in[3];
    const float* Bw   = (const float*)d_in[4];
    const float* scal = (const float*)d_in[5];
    float* out = (float*)d_out;

    const size_t INTER_B = (size_t)BT * RR * 2;              // 2 MB
    const size_t AT_B    = (size_t)NADP * RR * DIN * 2;      // 4 MB
    const size_t BT_B    = (size_t)NADP * DOUT * RR * 2;     // 4 MB

    if (ws_size >= INTER_B + AT_B + BT_B) {
        __bf16* inter2 = (__bf16*)d_ws;
        __bf16* At2    = (__bf16*)((char*)d_ws + INTER_B);
        __bf16* Bp     = (__bf16*)((char*)d_ws + INTER_B + AT_B);
        k_prep_a<<<dim3(1024), 256, 0, stream>>>(A, At2);
        k_prep_b<<<dim3(1024), 256, 0, stream>>>(Bw, Bp);
        k_xa<<<dim3(BT / 16),            256, 0, stream>>>(x, idx, At2, inter2);
        k_by<<<dim3(DOUT / 64, BT / 64), 256, 0, stream>>>(inter2, base, idx, Bp, scal, out);
    } else {
        __bf16* inter = (__bf16*)d_ws;
        k_xa_fb<<<dim3(BT / 32),            256, 0, stream>>>(x, idx, A, inter);
        k_by_fb<<<dim3(DOUT / 64, BT / 64), 256, 0, stream>>>(inter, base, idx, Bw, scal, out);
    }
}

// Round 9
// 234.784 us; speedup vs baseline: 1.5543x; 1.2153x over previous
//
#include <hip/hip_runtime.h>
#include <hip/hip_bf16.h>
#include <cstdint>
#include <cstddef>

#define BT    16384   // B*T
#define DIN   4096
#define DOUT  4096
#define RR    64
#define TSEQ  2048
#define NADP  8

typedef float  f32x4  __attribute__((ext_vector_type(4)));
typedef __bf16 bf16x8 __attribute__((ext_vector_type(8)));

static __device__ __forceinline__ unsigned short bf16_bits(float f) {
    return __builtin_bit_cast(unsigned short, (__bf16)f);
}

// inter2 swizzled layout: [mblk(1024)][rb(8)][mrow(16)][j(8)]
// holds inter[mblk*16+mrow][rb*8+j]
static __device__ __forceinline__ size_t i2_idx(int mblk, int rb, int mrow, int j) {
    return ((((size_t)mblk * 8 + rb) * 16 + mrow) * 8 + j);
}

// ---------------------------------------------------------------------------
// k_prep_a: At2[a][kb][r][j] = bf16(A[a][kb*8+j][r]).  (R8 verbatim, passed)
// ---------------------------------------------------------------------------
__global__ __launch_bounds__(256) void k_prep_a(
    const float* __restrict__ A, __bf16* __restrict__ At2)
{
    const int gtid = blockIdx.x * 256 + threadIdx.x;
    const int r  = gtid & 63;
    const int kb = (gtid >> 6) & (DIN / 8 - 1);
    const int a  = gtid >> 15;
    const float* __restrict__ src = A + (size_t)a * DIN * RR + (size_t)kb * 8 * RR + r;
    unsigned int u[4];
    #pragma unroll
    for (int p = 0; p < 4; ++p) {
        unsigned int lo = bf16_bits(src[(2 * p + 0) * RR]);
        unsigned int hi = bf16_bits(src[(2 * p + 1) * RR]);
        u[p] = lo | (hi << 16);
    }
    *(uint4*)&At2[(size_t)gtid * 8] = make_uint4(u[0], u[1], u[2], u[3]);
}

// ---------------------------------------------------------------------------
// k_prep_b: Bp[a][rb][o][j] = bf16(B[a][rb*8+j][o]).  (R8 verbatim, passed)
// ---------------------------------------------------------------------------
__global__ __launch_bounds__(256) void k_prep_b(
    const float* __restrict__ Bw, __bf16* __restrict__ Bp)
{
    const int gtid = blockIdx.x * 256 + threadIdx.x;
    const int o  = gtid & (DOUT - 1);
    const int rb = (gtid >> 12) & 7;
    const int a  = gtid >> 15;
    const float* __restrict__ src = Bw + (size_t)a * RR * DOUT + (size_t)rb * 8 * DOUT + o;
    unsigned int u[4];
    #pragma unroll
    for (int p = 0; p < 4; ++p) {
        unsigned int lo = bf16_bits(src[(2 * p + 0) * DOUT]);
        unsigned int hi = bf16_bits(src[(2 * p + 1) * DOUT]);
        u[p] = lo | (hi << 16);
    }
    *(uint4*)&Bp[(size_t)gtid * 8] = make_uint4(u[0], u[1], u[2], u[3]);
}

// ---------------------------------------------------------------------------
// k_xa: inter2 <- bf16( x @ A[a] ).  grid 256 blocks, 4 waves; wave w owns
// m-subtile [m0+w*16,+16) x 64 r, full K (R7 structure, passed). 4 MFMA
// chains share the x fragment; At2 fragments are 16B coalesced (R8 layout).
// NEW: explicit depth-4 software pipeline so ~12 load-insts stay in flight.
// ---------------------------------------------------------------------------
__global__ __launch_bounds__(256, 1) void k_xa(
    const float* __restrict__ x, const int* __restrict__ idx,
    const __bf16* __restrict__ At2, __bf16* __restrict__ inter2)
{
    const int m0   = blockIdx.x * 64;
    const int a    = idx[m0 / TSEQ];
    const int w    = threadIdx.x >> 6, lane = threadIdx.x & 63;
    const int mr   = lane & 15, kg = lane >> 4;
    const int mw   = m0 + w * 16;
    const float*  __restrict__ xrow = x   + (size_t)(mw + mr) * DIN + kg * 8;
    const __bf16* __restrict__ Aw   = At2 + (size_t)a * RR * DIN;

    f32x4 z = {0.f, 0.f, 0.f, 0.f};
    f32x4 acc[4] = {z, z, z, z};

    float4 px0[4], px1[4];
    bf16x8 pb[4][4];

    // prologue: stage steps 0..2
    #pragma unroll
    for (int s = 0; s < 3; ++s) {
        px0[s] = *(const float4*)(xrow + s * 32);
        px1[s] = *(const float4*)(xrow + s * 32 + 4);
        #pragma unroll
        for (int n = 0; n < 4; ++n)
            pb[s][n] = *(const bf16x8*)&Aw[((size_t)(s * 4 + kg) * 64 + n * 16 + mr) * 8];
    }

    #pragma unroll 4
    for (int ks = 0; ks < 128; ++ks) {
        const int pf = ks + 3;
        const int sp = pf & 3, sc = ks & 3;
        if (pf < 128) {
            px0[sp] = *(const float4*)(xrow + pf * 32);
            px1[sp] = *(const float4*)(xrow + pf * 32 + 4);
            #pragma unroll
            for (int n = 0; n < 4; ++n)
                pb[sp][n] = *(const bf16x8*)&Aw[((size_t)(pf * 4 + kg) * 64 + n * 16 + mr) * 8];
        }
        float4 u0 = px0[sc], u1 = px1[sc];
        bf16x8 af;
        af[0] = (__bf16)u0.x; af[1] = (__bf16)u0.y;
        af[2] = (__bf16)u0.z; af[3] = (__bf16)u0.w;
        af[4] = (__bf16)u1.x; af[5] = (__bf16)u1.y;
        af[6] = (__bf16)u1.z; af[7] = (__bf16)u1.w;
        #pragma unroll
        for (int n = 0; n < 4; ++n)
            acc[n] = __builtin_amdgcn_mfma_f32_16x16x32_bf16(af, pb[sc][n], acc[n], 0, 0, 0);
    }

    // D: row = kg*4+q (m within wave tile), col = n*16+mr (r). Store to i2.
    const int mblk = blockIdx.x * 4 + w;
    #pragma unroll
    for (int n = 0; n < 4; ++n) {
        const int rb = n * 2 + (mr >> 3), j = mr & 7;
        #pragma unroll
        for (int q = 0; q < 4; ++q)
            inter2[i2_idx(mblk, rb, kg * 4 + q, j)] = (__bf16)acc[n][q];
    }
}

// ---------------------------------------------------------------------------
// k_by: out = base + s * (inter @ B).  (R8 verbatim, passed, ~6.5 TB/s)
// ---------------------------------------------------------------------------
__global__ __launch_bounds__(256) void k_by(
    const __bf16* __restrict__ inter2, const float* __restrict__ base,
    const int* __restrict__ idx, const __bf16* __restrict__ Bp,
    const float* __restrict__ scal, float* __restrict__ out)
{
    const int o0 = blockIdx.x * 64;
    const int m0 = blockIdx.y * 64;
    const int a  = idx[m0 / TSEQ];
    const float s = scal[a];
    const __bf16* __restrict__ Ba = Bp + (size_t)a * RR * DOUT;
    const int lane = threadIdx.x & 63;
    const int w    = threadIdx.x >> 6;
    const int mr   = lane & 15, kg = lane >> 4;
    const int oc   = o0 + w * 16 + mr;

    f32x4 z = {0.f, 0.f, 0.f, 0.f};
    f32x4 acc[4] = {z, z, z, z};

    #pragma unroll
    for (int ksub = 0; ksub < 2; ++ksub) {
        const int rb = ksub * 4 + kg;
        bf16x8 bfA = *(const bf16x8*)&Ba[((size_t)rb * DOUT + oc) * 8];
        #pragma unroll
        for (int mt = 0; mt < 4; ++mt) {
            bf16x8 afB = *(const bf16x8*)&inter2[i2_idx(m0 / 16 + mt, rb, mr, 0)];
            acc[mt] = __builtin_amdgcn_mfma_f32_16x16x32_bf16(bfA, afB, acc[mt], 0, 0, 0);
        }
    }

    #pragma unroll
    for (int mt = 0; mt < 4; ++mt) {
        size_t off = (size_t)(m0 + mt * 16 + mr) * DOUT + o0 + w * 16 + kg * 4;
        float4 bv = *(const float4*)&base[off];
        float4 o;
        o.x = bv.x + s * acc[mt][0];
        o.y = bv.y + s * acc[mt][1];
        o.z = bv.z + s * acc[mt][2];
        o.w = bv.w + s * acc[mt][3];
        *(float4*)&out[off] = o;
    }
}

// ---------------------------------------------------------------------------
// Fallback kernels (R6 verbatim, 2 MB ws) if ws_size < 10 MB.
// ---------------------------------------------------------------------------
__global__ __launch_bounds__(256) void k_xa_fb(
    const float* __restrict__ x, const int* __restrict__ idx,
    const float* __restrict__ A, __bf16* __restrict__ inter)
{
    const int m0   = blockIdx.x * 32;
    const int a    = idx[m0 / TSEQ];
    const float* __restrict__ Aa = A + (size_t)a * DIN * RR;
    const int lane = threadIdx.x & 63;
    const int rw   = threadIdx.x >> 6;
    const int mr   = lane & 15, kg = lane >> 4;
    const int rcol = rw * 16 + mr;
    const float* __restrict__ xrow0 = x + (size_t)(m0 + mr) * DIN;
    const float* __restrict__ xrow1 = x + (size_t)(m0 + 16 + mr) * DIN;

    f32x4 acc0 = {0.f, 0.f, 0.f, 0.f};
    f32x4 acc1 = {0.f, 0.f, 0.f, 0.f};

    for (int k0 = 0; k0 < DIN; k0 += 64) {
        #pragma unroll
        for (int ksub = 0; ksub < 2; ++ksub) {
            const int koff = k0 + ksub * 32 + kg * 8;
            float4 u0 = *(const float4*)&xrow0[koff];
            float4 u1 = *(const float4*)&xrow0[koff + 4];
            float4 v0 = *(const float4*)&xrow1[koff];
            float4 v1 = *(const float4*)&xrow1[koff + 4];
            bf16x8 af0, af1;
            af0[0] = (__bf16)u0.x; af0[1] = (__bf16)u0.y;
            af0[2] = (__bf16)u0.z; af0[3] = (__bf16)u0.w;
            af0[4] = (__bf16)u1.x; af0[5] = (__bf16)u1.y;
            af0[6] = (__bf16)u1.z; af0[7] = (__bf16)u1.w;
            af1[0] = (__bf16)v0.x; af1[1] = (__bf16)v0.y;
            af1[2] = (__bf16)v0.z; af1[3] = (__bf16)v0.w;
            af1[4] = (__bf16)v1.x; af1[5] = (__bf16)v1.y;
            af1[6] = (__bf16)v1.z; af1[7] = (__bf16)v1.w;
            const float* ap = &Aa[(size_t)koff * RR + rcol];
            bf16x8 bf;
            bf[0] = (__bf16)ap[0 * RR]; bf[1] = (__bf16)ap[1 * RR];
            bf[2] = (__bf16)ap[2 * RR]; bf[3] = (__bf16)ap[3 * RR];
            bf[4] = (__bf16)ap[4 * RR]; bf[5] = (__bf16)ap[5 * RR];
            bf[6] = (__bf16)ap[6 * RR]; bf[7] = (__bf16)ap[7 * RR];
            acc0 = __builtin_amdgcn_mfma_f32_16x16x32_bf16(af0, bf, acc0, 0, 0, 0);
            acc1 = __builtin_amdgcn_mfma_f32_16x16x32_bf16(af1, bf, acc1, 0, 0, 0);
        }
    }
    #pragma unroll
    for (int q = 0; q < 4; ++q) {
        inter[(size_t)(m0 + kg * 4 + q) * RR + rcol]      = (__bf16)acc0[q];
        inter[(size_t)(m0 + 16 + kg * 4 + q) * RR + rcol] = (__bf16)acc1[q];
    }
}

__global__ __launch_bounds__(256) void k_by_fb(
    const __bf16* __restrict__ inter, const float* __restrict__ base,
    const int* __restrict__ idx, const float* __restrict__ Bw,
    const float* __restrict__ scal, float* __restrict__ out)
{
    const int o0 = blockIdx.x * 64;
    const int m0 = blockIdx.y * 64;
    const int a  = idx[m0 / TSEQ];
    const float s = scal[a];
    const float* __restrict__ Ba = Bw + (size_t)a * RR * DOUT;
    const int lane = threadIdx.x & 63;
    const int w    = threadIdx.x >> 6;
    const int mr   = lane & 15, kg = lane >> 4;
    const int oc   = o0 + w * 16 + mr;

    f32x4 z = {0.f, 0.f, 0.f, 0.f};
    f32x4 acc[4] = {z, z, z, z};

    #pragma unroll
    for (int ksub = 0; ksub < 2; ++ksub) {
        const int kb = ksub * 32 + kg * 8;
        const float* bp = &Ba[(size_t)kb * DOUT + oc];
        bf16x8 bf;
        bf[0] = (__bf16)bp[0 * DOUT]; bf[1] = (__bf16)bp[1 * DOUT];
        bf[2] = (__bf16)bp[2 * DOUT]; bf[3] = (__bf16)bp[3 * DOUT];
        bf[4] = (__bf16)bp[4 * DOUT]; bf[5] = (__bf16)bp[5 * DOUT];
        bf[6] = (__bf16)bp[6 * DOUT]; bf[7] = (__bf16)bp[7 * DOUT];
        #pragma unroll
        for (int mt = 0; mt < 4; ++mt) {
            bf16x8 af = *(const bf16x8*)&inter[(size_t)(m0 + mt * 16 + mr) * RR + kb];
            acc[mt] = __builtin_amdgcn_mfma_f32_16x16x32_bf16(af, bf, acc[mt], 0, 0, 0);
        }
    }
    #pragma unroll
    for (int mt = 0; mt < 4; ++mt) {
        #pragma unroll
        for (int q = 0; q < 4; ++q) {
            size_t off = (size_t)(m0 + mt * 16 + kg * 4 + q) * DOUT + oc;
            out[off] = base[off] + s * acc[mt][q];
        }
    }
}

// ---------------------------------------------------------------------------
extern "C" void kernel_launch(void* const* d_in, const int* in_sizes, int n_in,
                              void* d_out, int out_size, void* d_ws, size_t ws_size,
                              hipStream_t stream)
{
    const float* x    = (const float*)d_in[0];
    const float* base = (const float*)d_in[1];
    const int*   idx  = (const int*)  d_in[2];
    const float* A    = (const float*)d_in[3];
    const float* Bw   = (const float*)d_in[4];
    const float* scal = (const float*)d_in[5];
    float* out = (float*)d_out;

    const size_t INTER_B = (size_t)BT * RR * 2;              // 2 MB
    const size_t AT_B    = (size_t)NADP * RR * DIN * 2;      // 4 MB
    const size_t BT_B    = (size_t)NADP * DOUT * RR * 2;     // 4 MB

    if (ws_size >= INTER_B + AT_B + BT_B) {
        __bf16* inter2 = (__bf16*)d_ws;
        __bf16* At2    = (__bf16*)((char*)d_ws + INTER_B);
        __bf16* Bp     = (__bf16*)((char*)d_ws + INTER_B + AT_B);
        k_prep_a<<<dim3(1024), 256, 0, stream>>>(A, At2);
        k_prep_b<<<dim3(1024), 256, 0, stream>>>(Bw, Bp);
        k_xa<<<dim3(BT / 64),            256, 0, stream>>>(x, idx, At2, inter2);
        k_by<<<dim3(DOUT / 64, BT / 64), 256, 0, stream>>>(inter2, base, idx, Bp, scal, out);
    } else {
        __bf16* inter = (__bf16*)d_ws;
        k_xa_fb<<<dim3(BT / 32),            256, 0, stream>>>(x, idx, A, inter);
        k_by_fb<<<dim3(DOUT / 64, BT / 64), 256, 0, stream>>>(inter, base, idx, Bw, scal, out);
    }
}